// Round 10
// baseline (105.272 us; speedup 1.0000x reference)
//
#include <hip/hip_runtime.h>
#include <math.h>

#define NB 8
#define CH 16
#define LL 1024
#define DD 7
#define HH 16

typedef float    v2f  __attribute__((ext_vector_type(2)));
typedef float    v4f  __attribute__((ext_vector_type(4)));
typedef float    v16f __attribute__((ext_vector_type(16)));
typedef short    v8s  __attribute__((ext_vector_type(8)));
typedef unsigned v4u  __attribute__((ext_vector_type(4)));

__device__ inline unsigned bf16_rne(float f) {
    unsigned u = __builtin_bit_cast(unsigned, f);
    return (u + 0x7fffu + ((u >> 16) & 1u)) >> 16;
}

// quadratic-Schraudolph exp2: returns the fp32 BIT PATTERN of ~2^s as int.
// 2^s ~= bits( int( 2^23 * (s + C2*f*(1-f) + 127) ) ), f = fract(s).
// Ripple +-0.3%, continuous across exponent boundaries, ~zero mean; the
// softmax ratio shares the same weights top & bottom so bias cancels.
// 5 full-rate VALU ops -- replaces the 16-cyc/wave trans-pipe v_exp_f32.
__device__ inline int sexp2i(float s) {
#if __has_builtin(__builtin_amdgcn_fractf)
    float f = __builtin_amdgcn_fractf(s);
#else
    float f = s - floorf(s);
#endif
    float w = __builtin_fmaf(-f, f, f);                      // f*(1-f)
    float y = __builtin_fmaf(-0.34258f, w, s);
    return (int)__builtin_fmaf(y, 8388608.0f, 1065353216.0f); // 2^23, 127*2^23
}

// pack top-16 bits (bf16) of two fp32 bit patterns: [hi16(b) | hi16(a)]
__device__ inline unsigned pack_hi16(int ua, int ub) {
#if __has_builtin(__builtin_amdgcn_perm)
    return __builtin_amdgcn_perm((unsigned)ub, (unsigned)ua, 0x07060302u);
#else
    return (((unsigned)ua) >> 16) | (((unsigned)ub) & 0xffff0000u);
#endif
}

// ---------------------------------------------------------------------------
// Kernel 1: QKV projection via MFMA (bf16 inputs, fp32 accumulate). Unchanged
// from r6 (measured ~2.5 us). Output padded bf16 [mat][n][h][1024][8], Q
// pre-scaled by log2(e)/32, pad slot 7 zeroed.
// grid = 3*NB*16 = 384 blocks, 256 threads.
// ---------------------------------------------------------------------------
__global__ __launch_bounds__(256, 2) void qkv_proj(
    const float* __restrict__ x,
    const float* __restrict__ Wq, const float* __restrict__ bq,
    const float* __restrict__ Wk, const float* __restrict__ bk,
    const float* __restrict__ Wv, const float* __restrict__ bv,
    unsigned short* __restrict__ qkvb)
{
    __shared__ __align__(16) unsigned short Wb[112 * 136];  // 29.8 KB
    __shared__ __align__(16) unsigned short xb[64 * 136];   // 17.0 KB

    int bx  = blockIdx.x;
    int mat = bx / (NB * 16);
    int rem = bx % (NB * 16);
    int n   = rem / 16;
    int l0  = (rem % 16) * 64;

    const float* W = (mat == 0) ? Wq : (mat == 1) ? Wk : Wv;
    const float* b = (mat == 0) ? bq : (mat == 1) ? bk : bv;

    int tid = threadIdx.x;

    {
        const float4* Wsrc = (const float4*)W;
        for (int i4 = tid; i4 < 3136; i4 += 256) {
            int j  = i4 / 28;
            int ii = (i4 - j * 28) * 4;
            float4 w = Wsrc[i4];
            unsigned lo = bf16_rne(w.x) | (bf16_rne(w.y) << 16);
            unsigned hi = bf16_rne(w.z) | (bf16_rne(w.w) << 16);
            *(uint2*)&Wb[j * 136 + ii] = make_uint2(lo, hi);
        }
    }
    for (int idx = tid; idx < 64 * 112; idx += 256) {
        int c  = idx / 448;
        int r  = idx - c * 448;
        int l  = r / 7;
        int dd = r - l * 7;
        xb[l * 136 + c * 7 + dd] =
            (unsigned short)bf16_rne(x[((n * CH + c) * LL + l0 + l) * DD + dd]);
    }
    for (int idx = tid; idx < 64 * 16; idx += 256)
        xb[(idx >> 4) * 136 + 112 + (idx & 15)] = 0;
    for (int idx = tid; idx < 112 * 16; idx += 256)
        Wb[(idx >> 4) * 136 + 112 + (idx & 15)] = 0;

    {
        size_t base = ((size_t)(mat * NB + n) * HH) * (LL * 8);
        for (int idx = tid; idx < 1024; idx += 256) {
            int hh = idx >> 6, l = idx & 63;
            qkvb[base + (size_t)(hh * LL + l0 + l) * 8 + 7] = 0;
        }
    }
    __syncthreads();

    int wv = tid >> 6, lane = tid & 63, l15 = lane & 15, l4 = lane >> 4;

    const unsigned short* Arow = xb + (wv * 16 + l15) * 136 + l4 * 8;
    v8s af[4];
    #pragma unroll
    for (int k4 = 0; k4 < 4; ++k4) af[k4] = *(const v8s*)(Arow + k4 * 32);

    v4f acc[7];
    #pragma unroll
    for (int jt = 0; jt < 7; ++jt) acc[jt] = (v4f){0.f, 0.f, 0.f, 0.f};

    #pragma unroll
    for (int jt = 0; jt < 7; ++jt) {
        const unsigned short* Brow = Wb + (jt * 16 + l15) * 136 + l4 * 8;
        #pragma unroll
        for (int k4 = 0; k4 < 4; ++k4) {
            v8s bf = *(const v8s*)(Brow + k4 * 32);
            acc[jt] = __builtin_amdgcn_mfma_f32_16x16x32_bf16(af[k4], bf, acc[jt], 0, 0, 0);
        }
    }

    const float scale = (mat == 0) ? 0.0450842200277801f /* log2(e)/32 */ : 1.0f;
    size_t mbase = ((size_t)(mat * NB + n) * HH) * (LL * 8);
    #pragma unroll
    for (int jt = 0; jt < 7; ++jt) {
        int j   = jt * 16 + l15;
        int hh  = j / 7;
        int dim = j - hh * 7;
        float bj = b[j];
        int lrow = l0 + wv * 16 + l4 * 4;
        size_t rb = mbase + (size_t)hh * (LL * 8) + (size_t)lrow * 8 + dim;
        #pragma unroll
        for (int r = 0; r < 4; ++r) {
            float val = (acc[jt][r] + bj) * scale;
            qkvb[rb + (size_t)r * 8] = (unsigned short)bf16_rne(val);
        }
    }
}

// ---------------------------------------------------------------------------
// Kernel 2: MFMA flash attention (r8 structure), register-resident P, split-K.
//  512-thread blocks = 4 q-groups x 2 key-halves; wave owns 64 q x 512 keys.
//  S^T = mfma_32x32x16(A=K, B=Q); exp2 via full-rate VALU (sexp2i) instead of
//  the slow trans-pipe v_exp_f32; the int result's top 16 bits ARE the bf16 P
//  (one v_perm per pair). Key permutation absorbed in Vt column order;
//  V row 7 == 1.0 gives the denominator. Key-half partials combine via LDS
//  (plain fp32 adds - no max-rescale in this softmax).
// grid = NB*HH*4 = 512 blocks (n,h,qtile 256), 512 thr. LDS 41.3 KB -> 2/CU.
// ---------------------------------------------------------------------------
__global__ __launch_bounds__(512, 4) void attn(
    const unsigned short* __restrict__ qkvb, float* __restrict__ out)
{
    __shared__ __align__(16) unsigned short Kl[LL * 8];     // 16 KB
    __shared__ __align__(16) unsigned short Vt[8 * 1048];   // 16.4 KB, slot-permuted
    __shared__ __align__(16) float red[256 * 8];            // 8 KB partial exchange

    int bx = blockIdx.x;
    int qt = bx & 3, h = (bx >> 2) & 15, n = bx >> 6;
    int tid  = threadIdx.x;
    int wave = tid >> 6, lane = tid & 63;
    int l31 = lane & 31, g5 = lane >> 5;
    int g  = wave & 3;      // q-group
    int kh = wave >> 2;     // key half

    const unsigned short* Qg = qkvb + (size_t)((0 * NB + n) * HH + h) * (LL * 8);
    const unsigned short* Kg = qkvb + (size_t)((1 * NB + n) * HH + h) * (LL * 8);
    const unsigned short* Vg = qkvb + (size_t)((2 * NB + n) * HH + h) * (LL * 8);

    {   // stage K -> Kl (coalesced 16B, 1024 uint4 by 512 threads)
        const uint4* Ks = (const uint4*)Kg;
        uint4* Kd = (uint4*)Kl;
        Kd[tid]       = Ks[tid];
        Kd[tid + 512] = Ks[tid + 512];
    }
    if (tid < 256) {   // transpose + slot-permute V: global -> regs -> Vt[8][1048]
        const uint4* Vs = (const uint4*)Vg;
        uint4 r0 = Vs[4 * tid], r1 = Vs[4 * tid + 1];
        uint4 r2 = Vs[4 * tid + 2], r3 = Vs[4 * tid + 3];
        const unsigned* p0 = (const unsigned*)&r0;
        const unsigned* p1 = (const unsigned*)&r1;
        const unsigned* p2 = (const unsigned*)&r2;
        const unsigned* p3 = (const unsigned*)&r3;
        int col = ((tid >> 3) << 5) + ((tid & 1) << 3) + (((tid >> 1) & 1) << 2)
                + (((tid >> 2) & 1) << 4);
        #pragma unroll
        for (int d = 0; d < 7; ++d) {
            unsigned a0 = p0[d >> 1], a1 = p1[d >> 1], a2 = p2[d >> 1], a3 = p3[d >> 1];
            unsigned w0, w1;
            if (d & 1) { w0 = (a0 >> 16) | (a1 & 0xffff0000u); w1 = (a2 >> 16) | (a3 & 0xffff0000u); }
            else       { w0 = (a0 & 0xffffu) | (a1 << 16);     w1 = (a2 & 0xffffu) | (a3 << 16); }
            *(uint2*)&Vt[d * 1048 + col] = make_uint2(w0, w1);
        }
        *(uint2*)&Vt[7 * 1048 + col] = make_uint2(0x3f803f80u, 0x3f803f80u);  // ones row
    }
    __syncthreads();

    int q0 = qt * 256 + g * 64 + l31;
    v8s zero8 = {0, 0, 0, 0, 0, 0, 0, 0};
    v8s qfA = (lane < 32) ? *(const v8s*)(Qg + (size_t)q0 * 8)        : zero8;
    v8s qfB = (lane < 32) ? *(const v8s*)(Qg + (size_t)(q0 + 32) * 8) : zero8;

    const unsigned short* Vrow = Vt + (l31 & 7) * 1048 + g5 * 8;
    v16f accA = {}, accB = {};

    int kbase = kh * 512;   // this wave's 512 keys
    v8s kf = (lane < 32) ? *(const v8s*)(Kl + (kbase + l31) * 8) : zero8;

    #pragma unroll 2
    for (int c = 0; c < 16; ++c) {
        v16f sA = __builtin_amdgcn_mfma_f32_32x32x16_bf16(kf, qfA, (v16f){}, 0, 0, 0);
        v16f sB = __builtin_amdgcn_mfma_f32_32x32x16_bf16(kf, qfB, (v16f){}, 0, 0, 0);
        if (c < 15)
            kf = (lane < 32) ? *(const v8s*)(Kl + (kbase + (c + 1) * 32 + l31) * 8) : zero8;
        v8s va1 = *(const v8s*)(Vrow + (kbase + c * 32));        // slots 0..15
        v8s va2 = *(const v8s*)(Vrow + (kbase + c * 32) + 16);   // slots 16..31

        unsigned pkA[8], pkB[8];
        #pragma unroll
        for (int p = 0; p < 8; ++p)
            pkA[p] = pack_hi16(sexp2i(sA[2 * p]), sexp2i(sA[2 * p + 1]));
        #pragma unroll
        for (int p = 0; p < 8; ++p)
            pkB[p] = pack_hi16(sexp2i(sB[2 * p]), sexp2i(sB[2 * p + 1]));

        v8s pA1 = __builtin_bit_cast(v8s, (v4u){pkA[0], pkA[1], pkA[2], pkA[3]});
        v8s pA2 = __builtin_bit_cast(v8s, (v4u){pkA[4], pkA[5], pkA[6], pkA[7]});
        v8s pB1 = __builtin_bit_cast(v8s, (v4u){pkB[0], pkB[1], pkB[2], pkB[3]});
        v8s pB2 = __builtin_bit_cast(v8s, (v4u){pkB[4], pkB[5], pkB[6], pkB[7]});

        accA = __builtin_amdgcn_mfma_f32_32x32x16_bf16(va1, pA1, accA, 0, 0, 0);
        accA = __builtin_amdgcn_mfma_f32_32x32x16_bf16(va2, pA2, accA, 0, 0, 0);
        accB = __builtin_amdgcn_mfma_f32_32x32x16_bf16(va1, pB1, accB, 0, 0, 0);
        accB = __builtin_amdgcn_mfma_f32_32x32x16_bf16(va2, pB2, accB, 0, 0, 0);
    }

    // combine key halves: kh=1 writes regs 0..3 (dims 4*g5..4*g5+3), kh=0 adds
    if (kh == 1) {
        *(float4*)&red[(size_t)(g * 64 + l31) * 8 + 4 * g5] =
            make_float4(accA[0], accA[1], accA[2], accA[3]);
        *(float4*)&red[(size_t)(g * 64 + 32 + l31) * 8 + 4 * g5] =
            make_float4(accB[0], accB[1], accB[2], accB[3]);
    }
    __syncthreads();
    if (kh == 0) {
        float4 pa = *(const float4*)&red[(size_t)(g * 64 + l31) * 8 + 4 * g5];
        float4 pb = *(const float4*)&red[(size_t)(g * 64 + 32 + l31) * 8 + 4 * g5];
        accA[0] += pa.x; accA[1] += pa.y; accA[2] += pa.z; accA[3] += pa.w;
        accB[0] += pb.x; accB[1] += pb.y; accB[2] += pb.z; accB[3] += pb.w;

        size_t hb = (size_t)(n * HH + h) * LL * 7;
        {
            float rs = __shfl(accA[3], 32 + l31, 64);   // combined denominator
            float* base = out + hb + (size_t)q0 * 7;
            #pragma unroll
            for (int r = 0; r < 4; ++r) {
                int dim = 4 * g5 + r;
                if (dim < 7) base[dim] = accA[r] / rs;
            }
        }
        {
            float rs = __shfl(accB[3], 32 + l31, 64);
            float* base = out + hb + (size_t)(q0 + 32) * 7;
            #pragma unroll
            for (int r = 0; r < 4; ++r) {
                int dim = 4 * g5 + r;
                if (dim < 7) base[dim] = accB[r] / rs;
            }
        }
    }
}

extern "C" void kernel_launch(void* const* d_in, const int* in_sizes, int n_in,
                              void* d_out, int out_size, void* d_ws, size_t ws_size,
                              hipStream_t stream) {
    const float* x  = (const float*)d_in[0];
    const float* Wq = (const float*)d_in[1];
    const float* bq = (const float*)d_in[2];
    const float* Wk = (const float*)d_in[3];
    const float* bk = (const float*)d_in[4];
    const float* Wv = (const float*)d_in[5];
    const float* bv = (const float*)d_in[6];
    unsigned short* qkvb = (unsigned short*)d_ws;  // [3][8][16][1024][8] bf16 = 6 MB
    float* o = (float*)d_out;

    qkv_proj<<<dim3(3 * NB * 16), dim3(256), 0, stream>>>(x, Wq, bq, Wk, bk, Wv, bv, qkvb);
    attn<<<dim3(NB * HH * 4), dim3(512), 0, stream>>>(qkvb, o);
}

// Round 11
// 98.568 us; speedup vs baseline: 1.0680x; 1.0680x over previous
//
#include <hip/hip_runtime.h>
#include <math.h>

#define NB 8
#define CH 16
#define LL 1024
#define DD 7
#define HH 16

typedef float    v2f  __attribute__((ext_vector_type(2)));
typedef float    v4f  __attribute__((ext_vector_type(4)));
typedef float    v16f __attribute__((ext_vector_type(16)));
typedef short    v8s  __attribute__((ext_vector_type(8)));
typedef unsigned v4u  __attribute__((ext_vector_type(4)));

#if __has_builtin(__builtin_amdgcn_exp2f)
#define EXP2F(x) __builtin_amdgcn_exp2f(x)
#else
#define EXP2F(x) exp2f(x)
#endif

__device__ inline unsigned bf16_rne(float f) {
    unsigned u = __builtin_bit_cast(unsigned, f);
    return (u + 0x7fffu + ((u >> 16) & 1u)) >> 16;
}
// pack hi-16 (bf16, trunc) of two fp32: single v_perm_b32
__device__ inline unsigned pack_trunc(float a, float b) {
#if __has_builtin(__builtin_amdgcn_perm)
    return __builtin_amdgcn_perm(__builtin_bit_cast(unsigned, b),
                                 __builtin_bit_cast(unsigned, a), 0x07060302u);
#else
    return (__builtin_bit_cast(unsigned, a) >> 16) |
           (__builtin_bit_cast(unsigned, b) & 0xffff0000u);
#endif
}

// ---------------------------------------------------------------------------
// Kernel 1: QKV projection via MFMA (bf16 inputs, fp32 accumulate). Unchanged
// from r6 (measured ~2.5 us). Output padded bf16 [mat][n][h][1024][8], Q
// pre-scaled by log2(e)/32, pad slot 7 zeroed.
// grid = 3*NB*16 = 384 blocks, 256 threads.
// ---------------------------------------------------------------------------
__global__ __launch_bounds__(256, 2) void qkv_proj(
    const float* __restrict__ x,
    const float* __restrict__ Wq, const float* __restrict__ bq,
    const float* __restrict__ Wk, const float* __restrict__ bk,
    const float* __restrict__ Wv, const float* __restrict__ bv,
    unsigned short* __restrict__ qkvb)
{
    __shared__ __align__(16) unsigned short Wb[112 * 136];  // 29.8 KB
    __shared__ __align__(16) unsigned short xb[64 * 136];   // 17.0 KB

    int bx  = blockIdx.x;
    int mat = bx / (NB * 16);
    int rem = bx % (NB * 16);
    int n   = rem / 16;
    int l0  = (rem % 16) * 64;

    const float* W = (mat == 0) ? Wq : (mat == 1) ? Wk : Wv;
    const float* b = (mat == 0) ? bq : (mat == 1) ? bk : bv;

    int tid = threadIdx.x;

    {
        const float4* Wsrc = (const float4*)W;
        for (int i4 = tid; i4 < 3136; i4 += 256) {
            int j  = i4 / 28;
            int ii = (i4 - j * 28) * 4;
            float4 w = Wsrc[i4];
            unsigned lo = bf16_rne(w.x) | (bf16_rne(w.y) << 16);
            unsigned hi = bf16_rne(w.z) | (bf16_rne(w.w) << 16);
            *(uint2*)&Wb[j * 136 + ii] = make_uint2(lo, hi);
        }
    }
    for (int idx = tid; idx < 64 * 112; idx += 256) {
        int c  = idx / 448;
        int r  = idx - c * 448;
        int l  = r / 7;
        int dd = r - l * 7;
        xb[l * 136 + c * 7 + dd] =
            (unsigned short)bf16_rne(x[((n * CH + c) * LL + l0 + l) * DD + dd]);
    }
    for (int idx = tid; idx < 64 * 16; idx += 256)
        xb[(idx >> 4) * 136 + 112 + (idx & 15)] = 0;
    for (int idx = tid; idx < 112 * 16; idx += 256)
        Wb[(idx >> 4) * 136 + 112 + (idx & 15)] = 0;

    {
        size_t base = ((size_t)(mat * NB + n) * HH) * (LL * 8);
        for (int idx = tid; idx < 1024; idx += 256) {
            int hh = idx >> 6, l = idx & 63;
            qkvb[base + (size_t)(hh * LL + l0 + l) * 8 + 7] = 0;
        }
    }
    __syncthreads();

    int wv = tid >> 6, lane = tid & 63, l15 = lane & 15, l4 = lane >> 4;

    const unsigned short* Arow = xb + (wv * 16 + l15) * 136 + l4 * 8;
    v8s af[4];
    #pragma unroll
    for (int k4 = 0; k4 < 4; ++k4) af[k4] = *(const v8s*)(Arow + k4 * 32);

    v4f acc[7];
    #pragma unroll
    for (int jt = 0; jt < 7; ++jt) acc[jt] = (v4f){0.f, 0.f, 0.f, 0.f};

    #pragma unroll
    for (int jt = 0; jt < 7; ++jt) {
        const unsigned short* Brow = Wb + (jt * 16 + l15) * 136 + l4 * 8;
        #pragma unroll
        for (int k4 = 0; k4 < 4; ++k4) {
            v8s bf = *(const v8s*)(Brow + k4 * 32);
            acc[jt] = __builtin_amdgcn_mfma_f32_16x16x32_bf16(af[k4], bf, acc[jt], 0, 0, 0);
        }
    }

    const float scale = (mat == 0) ? 0.0450842200277801f /* log2(e)/32 */ : 1.0f;
    size_t mbase = ((size_t)(mat * NB + n) * HH) * (LL * 8);
    #pragma unroll
    for (int jt = 0; jt < 7; ++jt) {
        int j   = jt * 16 + l15;
        int hh  = j / 7;
        int dim = j - hh * 7;
        float bj = b[j];
        int lrow = l0 + wv * 16 + l4 * 4;
        size_t rb = mbase + (size_t)hh * (LL * 8) + (size_t)lrow * 8 + dim;
        #pragma unroll
        for (int r = 0; r < 4; ++r) {
            float val = (acc[jt][r] + bj) * scale;
            qkvb[rb + (size_t)r * 8] = (unsigned short)bf16_rne(val);
        }
    }
}

// ---------------------------------------------------------------------------
// Kernel 2: MFMA flash attention (r8 structure), register-resident P, split-K,
// A/B-ALTERNATING SOFTWARE PIPELINE: every 16-exp burst has the other
// q-group's S-MFMA already in the matrix pipe (sB(c) issues before exp(sA(c));
// sA(c+1) issues before exp(sB(c))), eliminating the per-burst MFMA-latency
// stall that left the trans pipe ~35% idle. Only 2 score tiles live at once.
//  512-thread blocks = 4 q-groups x 2 key-halves; wave owns 64 q x 512 keys.
//  exp on the TRANS pipe (v_exp_f32 - r10 proved VALU-exp regresses); pack =
//  one v_perm per pair. Key permutation absorbed in Vt column order;
//  V row 7 == 1.0 gives the denominator. Key-half partials combine via LDS
//  (plain fp32 adds - no max-rescale in this softmax).
// grid = NB*HH*4 = 512 blocks (n,h,qtile 256), 512 thr. LDS 41.3 KB -> 2/CU.
// ---------------------------------------------------------------------------
__global__ __launch_bounds__(512, 4) void attn(
    const unsigned short* __restrict__ qkvb, float* __restrict__ out)
{
    __shared__ __align__(16) unsigned short Kl[LL * 8];     // 16 KB
    __shared__ __align__(16) unsigned short Vt[8 * 1048];   // 16.4 KB, slot-permuted
    __shared__ __align__(16) float red[256 * 8];            // 8 KB partial exchange

    int bx = blockIdx.x;
    int qt = bx & 3, h = (bx >> 2) & 15, n = bx >> 6;
    int tid  = threadIdx.x;
    int wave = tid >> 6, lane = tid & 63;
    int l31 = lane & 31, g5 = lane >> 5;
    int g  = wave & 3;      // q-group
    int kh = wave >> 2;     // key half

    const unsigned short* Qg = qkvb + (size_t)((0 * NB + n) * HH + h) * (LL * 8);
    const unsigned short* Kg = qkvb + (size_t)((1 * NB + n) * HH + h) * (LL * 8);
    const unsigned short* Vg = qkvb + (size_t)((2 * NB + n) * HH + h) * (LL * 8);

    {   // stage K -> Kl (coalesced 16B, 1024 uint4 by 512 threads)
        const uint4* Ks = (const uint4*)Kg;
        uint4* Kd = (uint4*)Kl;
        Kd[tid]       = Ks[tid];
        Kd[tid + 512] = Ks[tid + 512];
    }
    if (tid < 256) {   // transpose + slot-permute V: global -> regs -> Vt[8][1048]
        const uint4* Vs = (const uint4*)Vg;
        uint4 r0 = Vs[4 * tid], r1 = Vs[4 * tid + 1];
        uint4 r2 = Vs[4 * tid + 2], r3 = Vs[4 * tid + 3];
        const unsigned* p0 = (const unsigned*)&r0;
        const unsigned* p1 = (const unsigned*)&r1;
        const unsigned* p2 = (const unsigned*)&r2;
        const unsigned* p3 = (const unsigned*)&r3;
        int col = ((tid >> 3) << 5) + ((tid & 1) << 3) + (((tid >> 1) & 1) << 2)
                + (((tid >> 2) & 1) << 4);
        #pragma unroll
        for (int d = 0; d < 7; ++d) {
            unsigned a0 = p0[d >> 1], a1 = p1[d >> 1], a2 = p2[d >> 1], a3 = p3[d >> 1];
            unsigned w0, w1;
            if (d & 1) { w0 = (a0 >> 16) | (a1 & 0xffff0000u); w1 = (a2 >> 16) | (a3 & 0xffff0000u); }
            else       { w0 = (a0 & 0xffffu) | (a1 << 16);     w1 = (a2 & 0xffffu) | (a3 << 16); }
            *(uint2*)&Vt[d * 1048 + col] = make_uint2(w0, w1);
        }
        *(uint2*)&Vt[7 * 1048 + col] = make_uint2(0x3f803f80u, 0x3f803f80u);  // ones row
    }
    __syncthreads();

    int q0 = qt * 256 + g * 64 + l31;
    v8s zero8 = {0, 0, 0, 0, 0, 0, 0, 0};
    v8s qfA = (lane < 32) ? *(const v8s*)(Qg + (size_t)q0 * 8)        : zero8;
    v8s qfB = (lane < 32) ? *(const v8s*)(Qg + (size_t)(q0 + 32) * 8) : zero8;

    const unsigned short* Vrow = Vt + (l31 & 7) * 1048 + g5 * 8;
    v16f accA = {}, accB = {};

    int kbase = kh * 512;   // this wave's 512 keys
    v8s kf  = (lane < 32) ? *(const v8s*)(Kl + (kbase + l31) * 8) : zero8;
    v8s kfn = kf;
    // prologue: S-MFMA for chunk 0's A group
    v16f sA = __builtin_amdgcn_mfma_f32_32x32x16_bf16(kf, qfA, (v16f){}, 0, 0, 0);

    #pragma unroll 2
    for (int c = 0; c < 16; ++c) {
        // prefetch next kf early (LDS latency hides under the exp bursts)
        if (c < 15)
            kfn = (lane < 32) ? *(const v8s*)(Kl + (kbase + (c + 1) * 32 + l31) * 8) : zero8;
        // issue B-group S-MFMA: it retires during A's exp burst
        v16f sB = __builtin_amdgcn_mfma_f32_32x32x16_bf16(kf, qfB, (v16f){}, 0, 0, 0);

        v8s va1 = *(const v8s*)(Vrow + (kbase + c * 32));        // slots 0..15
        v8s va2 = *(const v8s*)(Vrow + (kbase + c * 32) + 16);   // slots 16..31

        unsigned pk[8];
        #pragma unroll
        for (int p = 0; p < 8; ++p)
            pk[p] = pack_trunc(EXP2F(sA[2 * p]), EXP2F(sA[2 * p + 1]));
        {
            v8s p1 = __builtin_bit_cast(v8s, (v4u){pk[0], pk[1], pk[2], pk[3]});
            v8s p2 = __builtin_bit_cast(v8s, (v4u){pk[4], pk[5], pk[6], pk[7]});
            accA = __builtin_amdgcn_mfma_f32_32x32x16_bf16(va1, p1, accA, 0, 0, 0);
            accA = __builtin_amdgcn_mfma_f32_32x32x16_bf16(va2, p2, accA, 0, 0, 0);
        }

        // sA is dead: issue next chunk's A-group S-MFMA, retires during B's burst
        if (c < 15)
            sA = __builtin_amdgcn_mfma_f32_32x32x16_bf16(kfn, qfA, (v16f){}, 0, 0, 0);

        #pragma unroll
        for (int p = 0; p < 8; ++p)
            pk[p] = pack_trunc(EXP2F(sB[2 * p]), EXP2F(sB[2 * p + 1]));
        {
            v8s p1 = __builtin_bit_cast(v8s, (v4u){pk[0], pk[1], pk[2], pk[3]});
            v8s p2 = __builtin_bit_cast(v8s, (v4u){pk[4], pk[5], pk[6], pk[7]});
            accB = __builtin_amdgcn_mfma_f32_32x32x16_bf16(va1, p1, accB, 0, 0, 0);
            accB = __builtin_amdgcn_mfma_f32_32x32x16_bf16(va2, p2, accB, 0, 0, 0);
        }

        kf = kfn;
    }

    // combine key halves: kh=1 writes regs 0..3 (dims 4*g5..4*g5+3), kh=0 adds
    if (kh == 1) {
        *(float4*)&red[(size_t)(g * 64 + l31) * 8 + 4 * g5] =
            make_float4(accA[0], accA[1], accA[2], accA[3]);
        *(float4*)&red[(size_t)(g * 64 + 32 + l31) * 8 + 4 * g5] =
            make_float4(accB[0], accB[1], accB[2], accB[3]);
    }
    __syncthreads();
    if (kh == 0) {
        float4 pa = *(const float4*)&red[(size_t)(g * 64 + l31) * 8 + 4 * g5];
        float4 pb = *(const float4*)&red[(size_t)(g * 64 + 32 + l31) * 8 + 4 * g5];
        accA[0] += pa.x; accA[1] += pa.y; accA[2] += pa.z; accA[3] += pa.w;
        accB[0] += pb.x; accB[1] += pb.y; accB[2] += pb.z; accB[3] += pb.w;

        size_t hb = (size_t)(n * HH + h) * LL * 7;
        {
            float rs = __shfl(accA[3], 32 + l31, 64);   // combined denominator
            float* base = out + hb + (size_t)q0 * 7;
            #pragma unroll
            for (int r = 0; r < 4; ++r) {
                int dim = 4 * g5 + r;
                if (dim < 7) base[dim] = accA[r] / rs;
            }
        }
        {
            float rs = __shfl(accB[3], 32 + l31, 64);
            float* base = out + hb + (size_t)(q0 + 32) * 7;
            #pragma unroll
            for (int r = 0; r < 4; ++r) {
                int dim = 4 * g5 + r;
                if (dim < 7) base[dim] = accB[r] / rs;
            }
        }
    }
}

extern "C" void kernel_launch(void* const* d_in, const int* in_sizes, int n_in,
                              void* d_out, int out_size, void* d_ws, size_t ws_size,
                              hipStream_t stream) {
    const float* x  = (const float*)d_in[0];
    const float* Wq = (const float*)d_in[1];
    const float* bq = (const float*)d_in[2];
    const float* Wk = (const float*)d_in[3];
    const float* bk = (const float*)d_in[4];
    const float* Wv = (const float*)d_in[5];
    const float* bv = (const float*)d_in[6];
    unsigned short* qkvb = (unsigned short*)d_ws;  // [3][8][16][1024][8] bf16 = 6 MB
    float* o = (float*)d_out;

    qkv_proj<<<dim3(3 * NB * 16), dim3(256), 0, stream>>>(x, Wq, bq, Wk, bk, Wv, bv, qkvb);
    attn<<<dim3(NB * HH * 4), dim3(512), 0, stream>>>(qkvb, o);
}